// Round 11
// baseline (269.841 us; speedup 1.0000x reference)
//
#include <hip/hip_runtime.h>
#include <hip/hip_bf16.h>

#define NN 20000
#define CC 128

typedef __attribute__((ext_vector_type(8))) _Float16 half8;
typedef __attribute__((ext_vector_type(2))) _Float16 half2v;
typedef __attribute__((ext_vector_type(4))) float f32x4;

typedef const __attribute__((address_space(1))) void gv_t;
typedef __attribute__((address_space(3))) void sv_t;

// ---------- one-shot conversions: proj weights, We2, We1^T, x_prot->f16 ----------
__global__ __launch_bounds__(256) void conv_all_kernel(
    const float* __restrict__ Wf0, const float* __restrict__ Ws0,
    const float* __restrict__ Wf1, const float* __restrict__ Ws1,
    const float* __restrict__ Wf2, const float* __restrict__ Ws2,
    const float* __restrict__ Wf3, const float* __restrict__ Ws3,
    const float* __restrict__ We2, const float* __restrict__ We1,
    const float* __restrict__ xprot,
    _Float16* __restrict__ WctAll, _Float16* __restrict__ Wcte,
    _Float16* __restrict__ Wt1, _Float16* __restrict__ xp16) {
    int id = blockIdx.x * 256 + threadIdx.x;
    if (id < 262144) {
        int Lw = id >> 16;
        int i = id & 65535;
        int c = i & 511;
        int k = i >> 9;
        const float* Wfp = (Lw == 0) ? Wf0 : (Lw == 1) ? Wf1 : (Lw == 2) ? Wf2 : Wf3;
        const float* Wsp = (Lw == 0) ? Ws0 : (Lw == 1) ? Ws1 : (Lw == 2) ? Ws2 : Ws3;
        float v;
        if (c < 128) v = Wfp[k * 128 + c];
        else if (c < 256) v = Wfp[(128 + k) * 128 + (c - 128)];
        else if (c < 384) v = Wsp[k * 128 + (c - 256)];
        else v = Wsp[(128 + k) * 128 + (c - 384)];
        WctAll[Lw * 65536 + c * 128 + k] = (_Float16)v;
    } else if (id < 278528) {
        int i = id - 262144;
        int c = i & 127;
        int k = i >> 7;
        Wcte[c * 128 + k] = (_Float16)We2[k * 128 + c];
    } else if (id < 282624) {
        int i = id - 278528;
        int c = i & 127;
        int k = i >> 7;  // k < 32
        Wt1[c * 32 + k] = (_Float16)We1[k * 128 + c];
    } else {
        int i = id - 282624;  // < 640000
        xp16[i] = (_Float16)xprot[i];
    }
}

// ---------- encoder layer 1 via MFMA: (N x 32) @ (32 x 128) + b, relu -> f16 ----------
__global__ __launch_bounds__(256) void enc1_mfma_kernel(
    const _Float16* __restrict__ A, const _Float16* __restrict__ Wt1,
    const float* __restrict__ b, _Float16* __restrict__ Y) {
    int t = threadIdx.x;
    int wid = t >> 6, l = t & 63;
    int lr = l & 15, hi = l >> 4;
    int m0 = blockIdx.x * 128 + wid * 32;
    half8 af[2];
#pragma unroll
    for (int m = 0; m < 2; ++m) {
        int row = m0 + m * 16 + lr;
        half8 v = {0, 0, 0, 0, 0, 0, 0, 0};
        if (row < NN) v = *(const half8*)(A + (long)row * 32 + hi * 8);
        af[m] = v;
    }
    f32x4 acc[2][8] = {};
#pragma unroll
    for (int n = 0; n < 8; ++n) {
        int col = n * 16 + lr;
        half8 bg = *(const half8*)(Wt1 + (long)col * 32 + hi * 8);
#pragma unroll
        for (int m = 0; m < 2; ++m)
            acc[m][n] = __builtin_amdgcn_mfma_f32_16x16x32_f16(af[m], bg, acc[m][n], 0, 0, 0);
    }
#pragma unroll
    for (int n = 0; n < 8; ++n) {
        int col = n * 16 + lr;
        float bb = b[col];
#pragma unroll
        for (int m = 0; m < 2; ++m) {
#pragma unroll
            for (int q = 0; q < 4; ++q) {
                int row = m0 + m * 16 + hi * 4 + q;
                if (row < NN)
                    Y[(long)row * 128 + col] = (_Float16)fmaxf(acc[m][n][q] + bb, 0.0f);
            }
        }
    }
}

// ---------- MFMA GEMM: A+B staged via global_load_lds (r4/r8-proven coalescing) ----------
// mode 0 (proj): H row = 1024B:
//   [0,256)   Fd' f16 (log2e-scaled, +bf)     [256,512) Sd' f16 (log2e-scaled, +bs)
//   [512,1024) per-lane 8B: {vs0,vs1,us0,us1} bf16 where vs=2^-Fs', us=2^Ss'
// mode 1 (enc2): ncol=128; outF16 f16 only; bias0 on all cols
__global__ __launch_bounds__(256) void gemm_mfma_kernel(
    const _Float16* __restrict__ A, const _Float16* __restrict__ Wt,
    const float* __restrict__ bias0, const float* __restrict__ bias1,
    char* __restrict__ outH, _Float16* __restrict__ outF16, int M, int mode) {
    __shared__ _Float16 lds[32768];  // 64 KB: A [0,16384), B [16384,32768); epilogue reuse
    int t = threadIdx.x;
    int w = t >> 6, l = t & 63;
    int m0 = blockIdx.x * 128;
    int n0 = blockIdx.y * 128;
    {
        int rin = l >> 4;
        int cs = l & 15;
#pragma unroll
        for (int j = 0; j < 8; ++j) {
            int r = w * 32 + j * 4 + rin;
            int g = cs ^ (r & 7);
            int grow = m0 + r;
            if (grow > M - 1) grow = M - 1;
            __builtin_amdgcn_global_load_lds((gv_t*)(A + (long)grow * 128 + g * 8),
                (sv_t*)&lds[(w * 32 + j * 4) * 128], 16, 0, 0);
            __builtin_amdgcn_global_load_lds((gv_t*)(Wt + (long)(n0 + r) * 128 + g * 8),
                (sv_t*)&lds[16384 + (w * 32 + j * 4) * 128], 16, 0, 0);
        }
    }
    __syncthreads();
    int wm = w >> 1, wn = w & 1;
    int lr = l & 15, hi = l >> 4;
    f32x4 acc[4][4] = {};
#pragma unroll
    for (int ks = 0; ks < 4; ++ks) {
        int cidx = 4 * ks + hi;
        half8 af[4], bg[4];
#pragma unroll
        for (int m = 0; m < 4; ++m) {
            int row = wm * 64 + m * 16 + lr;
            af[m] = *(const half8*)(&lds[row * 128 + (cidx ^ (row & 7)) * 8]);
        }
#pragma unroll
        for (int n = 0; n < 4; ++n) {
            int row = wn * 64 + n * 16 + lr;
            bg[n] = *(const half8*)(&lds[16384 + row * 128 + (cidx ^ (row & 7)) * 8]);
        }
#pragma unroll
        for (int m = 0; m < 4; ++m)
#pragma unroll
            for (int n = 0; n < 4; ++n)
                acc[m][n] = __builtin_amdgcn_mfma_f32_16x16x32_f16(
                    af[m], bg[n], acc[m][n], 0, 0, 0);
    }
    if (mode == 0) {
        __syncthreads();
        const float S = 1.44269504f;
        bool isSrc = (n0 == 128) || (n0 == 384);
        float sgn = (n0 == 128) ? -S : S;
#pragma unroll
        for (int n = 0; n < 4; ++n) {
            int cl = wn * 64 + n * 16 + lr;
            int gcol = n0 + cl;
            float badd = (gcol < 128) ? bias0[gcol]
                       : ((gcol >= 256 && gcol < 384) ? bias1[gcol - 256] : 0.0f);
#pragma unroll
            for (int m = 0; m < 4; ++m)
#pragma unroll
                for (int q = 0; q < 4; ++q) {
                    int rl = wm * 64 + m * 16 + hi * 4 + q;
                    float v = acc[m][n][q] + badd;
                    if (!isSrc) {
                        lds[rl * 144 + cl] = (_Float16)(v * S);
                    } else {
                        float p = __builtin_amdgcn_exp2f(v * sgn);
                        uint b = __float_as_uint(p);
                        b = (b + 0x7FFFu + ((b >> 16) & 1u)) >> 16;  // rne to bf16
                        ((ushort*)lds)[rl * 144 + cl] = (ushort)b;
                    }
                }
        }
        __syncthreads();
        bool isSrc2 = (n0 == 128) || (n0 == 384);
#pragma unroll
        for (int i = 0; i < 8; ++i) {
            int id = t + 256 * i;
            int row = id >> 4, ch = id & 15;
            int grow = m0 + row;
            if (grow >= M) continue;
            half8 v = *(const half8*)(&lds[row * 144 + ch * 8]);
            if (!isSrc2) {
                int b2 = (n0 == 0) ? 0 : 256;
                *(half8*)(outH + (long)grow * 1024 + b2 + ch * 16) = v;
            } else {
                // 8 bf16 cols -> 4 lanes (4ch+j), 4B each at stride 8
                const uint* vp = (const uint*)&v;
                char* bp = outH + (long)grow * 1024 + 512 + ch * 32 +
                           ((n0 == 384) ? 4 : 0);
#pragma unroll
                for (int j = 0; j < 4; ++j) *(uint*)(bp + j * 8) = vp[j];
            }
        }
    } else {
#pragma unroll
        for (int n = 0; n < 4; ++n) {
            int gcol = n0 + wn * 64 + n * 16 + lr;
            float badd = bias0[gcol];
#pragma unroll
            for (int m = 0; m < 4; ++m)
#pragma unroll
                for (int q = 0; q < 4; ++q) {
                    int grow = m0 + wm * 64 + m * 16 + hi * 4 + q;
                    if (grow < M)
                        outF16[(long)grow * 128 + gcol] =
                            (_Float16)(acc[m][n][q] + badd);
                }
        }
    }
}

// ---------- bond CSR build ----------
__global__ __launch_bounds__(256) void count_int_kernel(
    const int* __restrict__ dst, int E, int* __restrict__ cnt) {
    int e = blockIdx.x * 256 + threadIdx.x;
    if (e < E) atomicAdd(&cnt[dst[e]], 1);
}

__global__ __launch_bounds__(1024) void scan_kernel(
    const int* __restrict__ cnt, int* __restrict__ off) {
    __shared__ int part[1024];
    int t = threadIdx.x;
    int base = t * 20;
    int loc[20];
    int s = 0;
#pragma unroll
    for (int i = 0; i < 20; ++i) {
        int idx = base + i;
        int v = (idx < NN) ? cnt[idx] : 0;
        loc[i] = s;
        s += v;
    }
    part[t] = s;
    __syncthreads();
    for (int d = 1; d < 1024; d <<= 1) {
        int v = (t >= d) ? part[t - d] : 0;
        __syncthreads();
        part[t] += v;
        __syncthreads();
    }
    int pre = (t > 0) ? part[t - 1] : 0;
#pragma unroll
    for (int i = 0; i < 20; ++i) {
        int idx = base + i;
        if (idx < NN) off[idx] = pre + loc[i];
    }
    if (t == 1023) off[NN] = part[1023];
}

__global__ __launch_bounds__(256) void scatter_kernel(
    const int* __restrict__ src, const int* __restrict__ dst, int E,
    const int* __restrict__ off, int* __restrict__ cur, int* __restrict__ eid) {
    int e = blockIdx.x * 256 + threadIdx.x;
    if (e < E) {
        int d = dst[e];
        int p = off[d] + atomicAdd(&cur[d], 1);
        eid[p] = src[e];
    }
}

// ---------- radius CSR offsets via binary search (dst sorted) ----------
__global__ __launch_bounds__(256) void csr_off_kernel(
    const int* __restrict__ dst, int E, int N1, int* __restrict__ off) {
    int n = blockIdx.x * 256 + threadIdx.x;
    if (n >= N1) return;
    int lo = 0, hi = E;
    while (lo < hi) {
        int mid = (lo + hi) >> 1;
        if (dst[mid] < n) lo = mid + 1;
        else hi = mid;
    }
    off[n] = lo;
}

// ---------- node-centric aggregation: factored exp2, SW-pipelined gathers ----------
// sigma = rcp(1 + vd*vs); softplus = ln2 * log2(1 + ud*us); ln2 folded into inv.
// x kept in f16 (xh); final layer (write_h==0) writes f32 to xoutF instead.
__global__ __launch_bounds__(256) void node_agg_kernel(
    const char* __restrict__ H, const int* __restrict__ srcArr,
    const int* __restrict__ off, _Float16* __restrict__ xh,
    float* __restrict__ xoutF, int write_h) {
    int n = blockIdx.x * 4 + (threadIdx.x >> 6);
    int nu = __builtin_amdgcn_readfirstlane(n);
    int l = threadIdx.x & 63;
    const char* hb = H + (long)nu * 1024;
    half2v xv = ((const half2v*)xh)[(long)nu * 64 + l];  // hoisted residual read
    half2v fdh = *(const half2v*)(hb + l * 4);
    half2v sdh = *(const half2v*)(hb + 256 + l * 4);
    float vd0 = __builtin_amdgcn_exp2f(-(float)fdh.x);
    float vd1 = __builtin_amdgcn_exp2f(-(float)fdh.y);
    float ud0 = __builtin_amdgcn_exp2f((float)sdh.x);
    float ud1 = __builtin_amdgcn_exp2f((float)sdh.y);
    int e0 = __builtin_amdgcn_readfirstlane(off[nu]);
    int e1 = __builtin_amdgcn_readfirstlane(off[nu + 1]);
    float ax = 0.0f, ay = 0.0f;
#define EDGEC(w0, w1)                                                        \
    {                                                                        \
        float vs0 = __uint_as_float((w0) << 16);                             \
        float vs1 = __uint_as_float((w0) & 0xFFFF0000u);                     \
        float us0 = __uint_as_float((w1) << 16);                             \
        float us1 = __uint_as_float((w1) & 0xFFFF0000u);                     \
        float rx = __builtin_amdgcn_rcpf(__builtin_fmaf(vd0, vs0, 1.0f));    \
        float ry = __builtin_amdgcn_rcpf(__builtin_fmaf(vd1, vs1, 1.0f));    \
        float px = __builtin_amdgcn_logf(__builtin_fmaf(ud0, us0, 1.0f));    \
        float py = __builtin_amdgcn_logf(__builtin_fmaf(ud1, us1, 1.0f));    \
        ax = __builtin_fmaf(rx, px, ax);                                     \
        ay = __builtin_fmaf(ry, py, ay);                                     \
    }
    int B = (e1 - e0) >> 3;  // full batches of 8
    int e = e0;
    if (B > 0) {
        uint2 wa[8], wb[8];
#pragma unroll
        for (int j = 0; j < 8; ++j) {
            int s = srcArr[e + j];
            wa[j] = *(const uint2*)(H + (long)s * 1024 + 512 + (long)l * 8);
        }
        for (int i = 0; i + 1 < B; ++i) {
            int eb = e + 8 * (i + 1);
            if (i & 1) {
#pragma unroll
                for (int j = 0; j < 8; ++j) {
                    int s = srcArr[eb + j];
                    wa[j] = *(const uint2*)(H + (long)s * 1024 + 512 + (long)l * 8);
                }
#pragma unroll
                for (int j = 0; j < 8; ++j) EDGEC(wb[j].x, wb[j].y)
            } else {
#pragma unroll
                for (int j = 0; j < 8; ++j) {
                    int s = srcArr[eb + j];
                    wb[j] = *(const uint2*)(H + (long)s * 1024 + 512 + (long)l * 8);
                }
#pragma unroll
                for (int j = 0; j < 8; ++j) EDGEC(wa[j].x, wa[j].y)
            }
        }
        if ((B - 1) & 1) {
#pragma unroll
            for (int j = 0; j < 8; ++j) EDGEC(wb[j].x, wb[j].y)
        } else {
#pragma unroll
            for (int j = 0; j < 8; ++j) EDGEC(wa[j].x, wa[j].y)
        }
        e += 8 * B;
    }
    for (; e + 3 < e1; e += 4) {
        uint2 w0, w1, w2, w3;
        int s0 = srcArr[e], s1 = srcArr[e + 1];
        int s2 = srcArr[e + 2], s3 = srcArr[e + 3];
        w0 = *(const uint2*)(H + (long)s0 * 1024 + 512 + (long)l * 8);
        w1 = *(const uint2*)(H + (long)s1 * 1024 + 512 + (long)l * 8);
        w2 = *(const uint2*)(H + (long)s2 * 1024 + 512 + (long)l * 8);
        w3 = *(const uint2*)(H + (long)s3 * 1024 + 512 + (long)l * 8);
        EDGEC(w0.x, w0.y) EDGEC(w1.x, w1.y) EDGEC(w2.x, w2.y) EDGEC(w3.x, w3.y)
    }
    for (; e < e1; ++e) {
        int s = srcArr[e];
        uint2 w0 = *(const uint2*)(H + (long)s * 1024 + 512 + (long)l * 8);
        EDGEC(w0.x, w0.y)
    }
#undef EDGEC
    float inv = 0.6931471805599453f *
                __builtin_amdgcn_rcpf(fmaxf((float)(e1 - e0), 1.0f));
    float ox = fmaxf((float)xv.x + ax * inv, 0.0f);
    float oy = fmaxf((float)xv.y + ay * inv, 0.0f);
    if (write_h) {
        half2v oh;
        oh.x = (_Float16)ox;
        oh.y = (_Float16)oy;
        ((half2v*)xh)[(long)nu * 64 + l] = oh;
    } else {
        ((float2*)xoutF)[(long)nu * 64 + l] = make_float2(ox, oy);
    }
}

extern "C" void kernel_launch(void* const* d_in, const int* in_sizes, int n_in,
                              void* d_out, int out_size, void* d_ws, size_t ws_size,
                              hipStream_t stream) {
    const float* x_prot = (const float*)d_in[0];
    const int* eb = (const int*)d_in[2];
    const int* er = (const int*)d_in[3];
    int Eb = in_sizes[2] / 2;
    int Er = in_sizes[3] / 2;
    const float* We1 = (const float*)d_in[4];
    const float* be1 = (const float*)d_in[5];
    const float* We2 = (const float*)d_in[6];
    const float* be2 = (const float*)d_in[7];
    const float* Wf[4]  = {(const float*)d_in[8],  (const float*)d_in[12],
                           (const float*)d_in[16], (const float*)d_in[20]};
    const float* bf[4]  = {(const float*)d_in[9],  (const float*)d_in[13],
                           (const float*)d_in[17], (const float*)d_in[21]};
    const float* Wsp[4] = {(const float*)d_in[10], (const float*)d_in[14],
                           (const float*)d_in[18], (const float*)d_in[22]};
    const float* bsp[4] = {(const float*)d_in[11], (const float*)d_in[15],
                           (const float*)d_in[19], (const float*)d_in[23]};

    char* ws = (char*)d_ws;
    _Float16*  xhf   = (_Float16*)ws;                     //  5,120,000
    char*      H     = (char*)(ws + 5120000);             // 20,480,000 (NN*1024B)
    _Float16*  xp16  = (_Float16*)(ws + 25600000);        //  1,280,000
    int*       cntI  = (int*)(ws + 26880000);             //     80,000
    int*       curB  = (int*)(ws + 26960000);             //     80,000
    int*       offB  = (int*)(ws + 27040000);             //     80,016
    int*       offR  = (int*)(ws + 27120016);             //     80,016
    int*       eidB  = (int*)(ws + 27200032);             //    320,000
    _Float16*  WctAll= (_Float16*)(ws + 27520032);        //    524,288
    _Float16*  Wcte  = (_Float16*)(ws + 28044320);        //     32,768
    _Float16*  Wt1   = (_Float16*)(ws + 28077088);        //      8,192

    const int* srcB = eb;
    const int* dstB = eb + Eb;
    const int* srcR = er;

    conv_all_kernel<<<3604, 256, 0, stream>>>(
        Wf[0], Wsp[0], Wf[1], Wsp[1], Wf[2], Wsp[2], Wf[3], Wsp[3],
        We2, We1, x_prot, WctAll, Wcte, Wt1, xp16);

    hipMemsetAsync(cntI, 0, 160000, stream);
    count_int_kernel<<<(Eb + 255) / 256, 256, 0, stream>>>(dstB, Eb, cntI);
    scan_kernel<<<1, 1024, 0, stream>>>(cntI, offB);
    scatter_kernel<<<(Eb + 255) / 256, 256, 0, stream>>>(srcB, dstB, Eb, offB, curB, eidB);
    csr_off_kernel<<<(NN + 256) / 256, 256, 0, stream>>>(er + Er, Er, NN + 1, offR);

    // encoder: enc1 -> f16 scratch (H), enc2 via MFMA -> xhf (f16 only)
    enc1_mfma_kernel<<<157, 256, 0, stream>>>(xp16, Wt1, be1, (_Float16*)H);
    {
        dim3 g(157, 1);
        gemm_mfma_kernel<<<g, 256, 0, stream>>>((_Float16*)H, Wcte, be2, be2,
                                                nullptr, xhf, NN, 1);
    }

    for (int L = 0; L < 4; ++L) {
        dim3 g(157, 4);
        gemm_mfma_kernel<<<g, 256, 0, stream>>>(xhf, WctAll + L * 65536, bf[L],
                                                bsp[L], H, nullptr, NN, 0);
        const int* sArr = (L < 2) ? eidB : srcR;
        const int* oArr = (L < 2) ? offB : offR;
        node_agg_kernel<<<NN / 4, 256, 0, stream>>>(H, sArr, oArr, xhf,
                                                    (float*)d_out,
                                                    (L == 3) ? 0 : 1);
    }
    (void)n_in; (void)out_size; (void)ws_size;
}

// Round 12
// 241.229 us; speedup vs baseline: 1.1186x; 1.1186x over previous
//
#include <hip/hip_runtime.h>
#include <hip/hip_bf16.h>

#define NN 20000
#define CC 128

typedef __attribute__((ext_vector_type(8))) _Float16 half8;
typedef __attribute__((ext_vector_type(2))) _Float16 half2v;
typedef __attribute__((ext_vector_type(4))) float f32x4;

typedef const __attribute__((address_space(1))) void gv_t;
typedef __attribute__((address_space(3))) void sv_t;

// ---------- one-shot conversions: proj weights, We2, We1^T, x_prot->f16 ----------
__global__ __launch_bounds__(256) void conv_all_kernel(
    const float* __restrict__ Wf0, const float* __restrict__ Ws0,
    const float* __restrict__ Wf1, const float* __restrict__ Ws1,
    const float* __restrict__ Wf2, const float* __restrict__ Ws2,
    const float* __restrict__ Wf3, const float* __restrict__ Ws3,
    const float* __restrict__ We2, const float* __restrict__ We1,
    const float* __restrict__ xprot,
    _Float16* __restrict__ WctAll, _Float16* __restrict__ Wcte,
    _Float16* __restrict__ Wt1, _Float16* __restrict__ xp16) {
    int id = blockIdx.x * 256 + threadIdx.x;
    if (id < 262144) {
        int Lw = id >> 16;
        int i = id & 65535;
        int c = i & 511;
        int k = i >> 9;
        const float* Wfp = (Lw == 0) ? Wf0 : (Lw == 1) ? Wf1 : (Lw == 2) ? Wf2 : Wf3;
        const float* Wsp = (Lw == 0) ? Ws0 : (Lw == 1) ? Ws1 : (Lw == 2) ? Ws2 : Ws3;
        float v;
        if (c < 128) v = Wfp[k * 128 + c];
        else if (c < 256) v = Wfp[(128 + k) * 128 + (c - 128)];
        else if (c < 384) v = Wsp[k * 128 + (c - 256)];
        else v = Wsp[(128 + k) * 128 + (c - 384)];
        WctAll[Lw * 65536 + c * 128 + k] = (_Float16)v;
    } else if (id < 278528) {
        int i = id - 262144;
        int c = i & 127;
        int k = i >> 7;
        Wcte[c * 128 + k] = (_Float16)We2[k * 128 + c];
    } else if (id < 282624) {
        int i = id - 278528;
        int c = i & 127;
        int k = i >> 7;  // k < 32
        Wt1[c * 32 + k] = (_Float16)We1[k * 128 + c];
    } else {
        int i = id - 282624;  // < 640000
        xp16[i] = (_Float16)xprot[i];
    }
}

// ---------- encoder layer 1 via MFMA: (N x 32) @ (32 x 128) + b, relu -> f16 ----------
__global__ __launch_bounds__(256) void enc1_mfma_kernel(
    const _Float16* __restrict__ A, const _Float16* __restrict__ Wt1,
    const float* __restrict__ b, _Float16* __restrict__ Y) {
    int t = threadIdx.x;
    int wid = t >> 6, l = t & 63;
    int lr = l & 15, hi = l >> 4;
    int m0 = blockIdx.x * 128 + wid * 32;
    half8 af[2];
#pragma unroll
    for (int m = 0; m < 2; ++m) {
        int row = m0 + m * 16 + lr;
        half8 v = {0, 0, 0, 0, 0, 0, 0, 0};
        if (row < NN) v = *(const half8*)(A + (long)row * 32 + hi * 8);
        af[m] = v;
    }
    f32x4 acc[2][8] = {};
#pragma unroll
    for (int n = 0; n < 8; ++n) {
        int col = n * 16 + lr;
        half8 bg = *(const half8*)(Wt1 + (long)col * 32 + hi * 8);
#pragma unroll
        for (int m = 0; m < 2; ++m)
            acc[m][n] = __builtin_amdgcn_mfma_f32_16x16x32_f16(af[m], bg, acc[m][n], 0, 0, 0);
    }
#pragma unroll
    for (int n = 0; n < 8; ++n) {
        int col = n * 16 + lr;
        float bb = b[col];
#pragma unroll
        for (int m = 0; m < 2; ++m) {
#pragma unroll
            for (int q = 0; q < 4; ++q) {
                int row = m0 + m * 16 + hi * 4 + q;
                if (row < NN)
                    Y[(long)row * 128 + col] = (_Float16)fmaxf(acc[m][n][q] + bb, 0.0f);
            }
        }
    }
}

// ---------- MFMA GEMM: A+B staged via global_load_lds (r4/r8-proven) ----------
// mode 0 (proj):
//   n0==0   -> Hd[row] bytes [0,256):   Fd' f16 (log2e-scaled, +bf)
//   n0==256 -> Hd[row] bytes [256,512): Sd' f16 (log2e-scaled, +bs)
//   n0==128 -> Hf[row] bytes [0,256):   vs = 2^-Fs' bf16
//   n0==384 -> Hf[row] bytes [256,512): us = 2^+Ss' bf16
//   All stores: contiguous 16B half8 per lane (r8-proven pattern).
// mode 1 (enc2): ncol=128; outF f32 + outF16 f16 (raw); bias0 on all cols
__global__ __launch_bounds__(256) void gemm_mfma_kernel(
    const _Float16* __restrict__ A, const _Float16* __restrict__ Wt,
    const float* __restrict__ bias0, const float* __restrict__ bias1,
    char* __restrict__ outHd, char* __restrict__ outHf,
    float* __restrict__ outF, _Float16* __restrict__ outF16, int M, int mode) {
    __shared__ _Float16 lds[32768];  // 64 KB: A [0,16384), B [16384,32768); epilogue reuse
    int t = threadIdx.x;
    int w = t >> 6, l = t & 63;
    int m0 = blockIdx.x * 128;
    int n0 = blockIdx.y * 128;
    {
        int rin = l >> 4;
        int cs = l & 15;
#pragma unroll
        for (int j = 0; j < 8; ++j) {
            int r = w * 32 + j * 4 + rin;
            int g = cs ^ (r & 7);
            int grow = m0 + r;
            if (grow > M - 1) grow = M - 1;
            __builtin_amdgcn_global_load_lds((gv_t*)(A + (long)grow * 128 + g * 8),
                (sv_t*)&lds[(w * 32 + j * 4) * 128], 16, 0, 0);
            __builtin_amdgcn_global_load_lds((gv_t*)(Wt + (long)(n0 + r) * 128 + g * 8),
                (sv_t*)&lds[16384 + (w * 32 + j * 4) * 128], 16, 0, 0);
        }
    }
    __syncthreads();
    int wm = w >> 1, wn = w & 1;
    int lr = l & 15, hi = l >> 4;
    f32x4 acc[4][4] = {};
#pragma unroll
    for (int ks = 0; ks < 4; ++ks) {
        int cidx = 4 * ks + hi;
        half8 af[4], bg[4];
#pragma unroll
        for (int m = 0; m < 4; ++m) {
            int row = wm * 64 + m * 16 + lr;
            af[m] = *(const half8*)(&lds[row * 128 + (cidx ^ (row & 7)) * 8]);
        }
#pragma unroll
        for (int n = 0; n < 4; ++n) {
            int row = wn * 64 + n * 16 + lr;
            bg[n] = *(const half8*)(&lds[16384 + row * 128 + (cidx ^ (row & 7)) * 8]);
        }
#pragma unroll
        for (int m = 0; m < 4; ++m)
#pragma unroll
            for (int n = 0; n < 4; ++n)
                acc[m][n] = __builtin_amdgcn_mfma_f32_16x16x32_f16(
                    af[m], bg[n], acc[m][n], 0, 0, 0);
    }
    if (mode == 0) {
        __syncthreads();
        const float S = 1.44269504f;
        bool isSrc = (n0 == 128) || (n0 == 384);
        float sgn = (n0 == 128) ? -S : S;
#pragma unroll
        for (int n = 0; n < 4; ++n) {
            int cl = wn * 64 + n * 16 + lr;
            int gcol = n0 + cl;
            float badd = (gcol < 128) ? bias0[gcol]
                       : ((gcol >= 256 && gcol < 384) ? bias1[gcol - 256] : 0.0f);
#pragma unroll
            for (int m = 0; m < 4; ++m)
#pragma unroll
                for (int q = 0; q < 4; ++q) {
                    int rl = wm * 64 + m * 16 + hi * 4 + q;
                    float v = acc[m][n][q] + badd;
                    if (!isSrc) {
                        lds[rl * 144 + cl] = (_Float16)(v * S);
                    } else {
                        float p = __builtin_amdgcn_exp2f(v * sgn);
                        uint b = __float_as_uint(p);
                        b = (b + 0x7FFFu + ((b >> 16) & 1u)) >> 16;  // rne to bf16
                        ((ushort*)lds)[rl * 144 + cl] = (ushort)b;
                    }
                }
        }
        __syncthreads();
        char* obase = ((n0 == 128) || (n0 == 384)) ? outHf : outHd;
        int half = ((n0 == 0) || (n0 == 128)) ? 0 : 256;
#pragma unroll
        for (int i = 0; i < 8; ++i) {
            int id = t + 256 * i;
            int row = id >> 4, ch = id & 15;
            int grow = m0 + row;
            if (grow < M) {
                half8 v = *(const half8*)(&lds[row * 144 + ch * 8]);
                *(half8*)(obase + (long)grow * 512 + half + ch * 16) = v;
            }
        }
    } else {
#pragma unroll
        for (int n = 0; n < 4; ++n) {
            int gcol = n0 + wn * 64 + n * 16 + lr;
            float badd = bias0[gcol];
#pragma unroll
            for (int m = 0; m < 4; ++m)
#pragma unroll
                for (int q = 0; q < 4; ++q) {
                    int grow = m0 + wm * 64 + m * 16 + hi * 4 + q;
                    if (grow < M) {
                        float v = acc[m][n][q] + badd;
                        outF[(long)grow * 128 + gcol] = v;
                        outF16[(long)grow * 128 + gcol] = (_Float16)v;
                    }
                }
        }
    }
}

// ---------- bond CSR build ----------
__global__ __launch_bounds__(256) void count_int_kernel(
    const int* __restrict__ dst, int E, int* __restrict__ cnt) {
    int e = blockIdx.x * 256 + threadIdx.x;
    if (e < E) atomicAdd(&cnt[dst[e]], 1);
}

__global__ __launch_bounds__(1024) void scan_kernel(
    const int* __restrict__ cnt, int* __restrict__ off) {
    __shared__ int part[1024];
    int t = threadIdx.x;
    int base = t * 20;
    int loc[20];
    int s = 0;
#pragma unroll
    for (int i = 0; i < 20; ++i) {
        int idx = base + i;
        int v = (idx < NN) ? cnt[idx] : 0;
        loc[i] = s;
        s += v;
    }
    part[t] = s;
    __syncthreads();
    for (int d = 1; d < 1024; d <<= 1) {
        int v = (t >= d) ? part[t - d] : 0;
        __syncthreads();
        part[t] += v;
        __syncthreads();
    }
    int pre = (t > 0) ? part[t - 1] : 0;
#pragma unroll
    for (int i = 0; i < 20; ++i) {
        int idx = base + i;
        if (idx < NN) off[idx] = pre + loc[i];
    }
    if (t == 1023) off[NN] = part[1023];
}

__global__ __launch_bounds__(256) void scatter_kernel(
    const int* __restrict__ src, const int* __restrict__ dst, int E,
    const int* __restrict__ off, int* __restrict__ cur, int* __restrict__ eid) {
    int e = blockIdx.x * 256 + threadIdx.x;
    if (e < E) {
        int d = dst[e];
        int p = off[d] + atomicAdd(&cur[d], 1);
        eid[p] = src[e];
    }
}

// ---------- radius CSR offsets via binary search (dst sorted) ----------
__global__ __launch_bounds__(256) void csr_off_kernel(
    const int* __restrict__ dst, int E, int N1, int* __restrict__ off) {
    int n = blockIdx.x * 256 + threadIdx.x;
    if (n >= N1) return;
    int lo = 0, hi = E;
    while (lo < hi) {
        int mid = (lo + hi) >> 1;
        if (dst[mid] < n) lo = mid + 1;
        else hi = mid;
    }
    off[n] = lo;
}

// ---------- node-centric aggregation: factored exp2 (r8 loop structure) ----------
// sigma = rcp(1 + vd*vs); softplus = ln2 * log2(1 + ud*us); ln2 folded into inv.
__global__ __launch_bounds__(256) void node_agg_kernel(
    const char* __restrict__ Hd, const char* __restrict__ Hf,
    const int* __restrict__ srcArr, const int* __restrict__ off,
    const float* __restrict__ xin, float* __restrict__ xout,
    _Float16* __restrict__ xh, int write_h) {
    int n = blockIdx.x * 4 + (threadIdx.x >> 6);
    int nu = __builtin_amdgcn_readfirstlane(n);
    int l = threadIdx.x & 63;
    const char* hb = Hd + (long)nu * 512;
    half2v fdh = *(const half2v*)(hb + l * 4);
    half2v sdh = *(const half2v*)(hb + 256 + l * 4);
    float vd0 = __builtin_amdgcn_exp2f(-(float)fdh.x);
    float vd1 = __builtin_amdgcn_exp2f(-(float)fdh.y);
    float ud0 = __builtin_amdgcn_exp2f((float)sdh.x);
    float ud1 = __builtin_amdgcn_exp2f((float)sdh.y);
    int e0 = __builtin_amdgcn_readfirstlane(off[nu]);
    int e1 = __builtin_amdgcn_readfirstlane(off[nu + 1]);
    float ax = 0.0f, ay = 0.0f;
#define EDGEC(wv, wu)                                                        \
    {                                                                        \
        float vs0 = __uint_as_float((wv) << 16);                             \
        float vs1 = __uint_as_float((wv) & 0xFFFF0000u);                     \
        float us0 = __uint_as_float((wu) << 16);                             \
        float us1 = __uint_as_float((wu) & 0xFFFF0000u);                     \
        float rx = __builtin_amdgcn_rcpf(__builtin_fmaf(vd0, vs0, 1.0f));    \
        float ry = __builtin_amdgcn_rcpf(__builtin_fmaf(vd1, vs1, 1.0f));    \
        float px = __builtin_amdgcn_logf(__builtin_fmaf(ud0, us0, 1.0f));    \
        float py = __builtin_amdgcn_logf(__builtin_fmaf(ud1, us1, 1.0f));    \
        ax = __builtin_fmaf(rx, px, ax);                                     \
        ay = __builtin_fmaf(ry, py, ay);                                     \
    }
    int e = e0;
    for (; e + 7 < e1; e += 8) {
        uint wv[8], wu[8];
#pragma unroll
        for (int j = 0; j < 8; ++j) {
            int s = srcArr[e + j];
            const char* hs = Hf + (long)s * 512 + (long)l * 4;
            wv[j] = *(const uint*)(hs);
            wu[j] = *(const uint*)(hs + 256);
        }
#pragma unroll
        for (int j = 0; j < 8; ++j) EDGEC(wv[j], wu[j])
    }
    for (; e + 1 < e1; e += 2) {
        int s0 = srcArr[e], s1 = srcArr[e + 1];
        const char* h0 = Hf + (long)s0 * 512 + (long)l * 4;
        const char* h1 = Hf + (long)s1 * 512 + (long)l * 4;
        uint v0 = *(const uint*)(h0), u0 = *(const uint*)(h0 + 256);
        uint v1 = *(const uint*)(h1), u1 = *(const uint*)(h1 + 256);
        EDGEC(v0, u0) EDGEC(v1, u1)
    }
    if (e < e1) {
        int s0 = srcArr[e];
        const char* h0 = Hf + (long)s0 * 512 + (long)l * 4;
        uint v0 = *(const uint*)(h0), u0 = *(const uint*)(h0 + 256);
        EDGEC(v0, u0)
    }
#undef EDGEC
    // inv = ln2 / cnt  (folds softplus' ln2 back in)
    float inv = 0.6931471805599453f *
                __builtin_amdgcn_rcpf(fmaxf((float)(e1 - e0), 1.0f));
    float2 xv = ((const float2*)xin)[(long)nu * 64 + l];
    float ox = fmaxf(xv.x + ax * inv, 0.0f);
    float oy = fmaxf(xv.y + ay * inv, 0.0f);
    ((float2*)xout)[(long)nu * 64 + l] = make_float2(ox, oy);
    if (write_h) {
        half2v oh;
        oh.x = (_Float16)ox;
        oh.y = (_Float16)oy;
        ((half2v*)xh)[(long)nu * 64 + l] = oh;
    }
}

extern "C" void kernel_launch(void* const* d_in, const int* in_sizes, int n_in,
                              void* d_out, int out_size, void* d_ws, size_t ws_size,
                              hipStream_t stream) {
    const float* x_prot = (const float*)d_in[0];
    const int* eb = (const int*)d_in[2];
    const int* er = (const int*)d_in[3];
    int Eb = in_sizes[2] / 2;
    int Er = in_sizes[3] / 2;
    const float* We1 = (const float*)d_in[4];
    const float* be1 = (const float*)d_in[5];
    const float* We2 = (const float*)d_in[6];
    const float* be2 = (const float*)d_in[7];
    const float* Wf[4]  = {(const float*)d_in[8],  (const float*)d_in[12],
                           (const float*)d_in[16], (const float*)d_in[20]};
    const float* bf[4]  = {(const float*)d_in[9],  (const float*)d_in[13],
                           (const float*)d_in[17], (const float*)d_in[21]};
    const float* Wsp[4] = {(const float*)d_in[10], (const float*)d_in[14],
                           (const float*)d_in[18], (const float*)d_in[22]};
    const float* bsp[4] = {(const float*)d_in[11], (const float*)d_in[15],
                           (const float*)d_in[19], (const float*)d_in[23]};

    char* ws = (char*)d_ws;
    float*     xbuf  = (float*)ws;                        // 10,240,000
    _Float16*  xhf   = (_Float16*)(ws + 10240000);        //  5,120,000
    char*      Hd    = (char*)(ws + 15360000);            // 10,240,000 (NN*512B)
    char*      Hf    = (char*)(ws + 25600000);            // 10,240,000 (NN*512B)
    _Float16*  xp16  = (_Float16*)(ws + 35840000);        //  1,280,000
    int*       cntI  = (int*)(ws + 37120000);             //     80,000
    int*       curB  = (int*)(ws + 37200000);             //     80,000
    int*       offB  = (int*)(ws + 37280000);             //     80,016
    int*       offR  = (int*)(ws + 37360016);             //     80,016
    int*       eidB  = (int*)(ws + 37440032);             //    320,000
    _Float16*  WctAll= (_Float16*)(ws + 37760032);        //    524,288
    _Float16*  Wcte  = (_Float16*)(ws + 38284320);        //     32,768
    _Float16*  Wt1   = (_Float16*)(ws + 38317088);        //      8,192

    const int* srcB = eb;
    const int* dstB = eb + Eb;
    const int* srcR = er;

    conv_all_kernel<<<3604, 256, 0, stream>>>(
        Wf[0], Wsp[0], Wf[1], Wsp[1], Wf[2], Wsp[2], Wf[3], Wsp[3],
        We2, We1, x_prot, WctAll, Wcte, Wt1, xp16);

    hipMemsetAsync(cntI, 0, 160000, stream);
    count_int_kernel<<<(Eb + 255) / 256, 256, 0, stream>>>(dstB, Eb, cntI);
    scan_kernel<<<1, 1024, 0, stream>>>(cntI, offB);
    scatter_kernel<<<(Eb + 255) / 256, 256, 0, stream>>>(srcB, dstB, Eb, offB, curB, eidB);
    csr_off_kernel<<<(NN + 256) / 256, 256, 0, stream>>>(er + Er, Er, NN + 1, offR);

    // encoder: enc1 -> f16 scratch (Hd), enc2 via MFMA -> xbuf + xhf
    enc1_mfma_kernel<<<157, 256, 0, stream>>>(xp16, Wt1, be1, (_Float16*)Hd);
    {
        dim3 g(157, 1);
        gemm_mfma_kernel<<<g, 256, 0, stream>>>((_Float16*)Hd, Wcte, be2, be2,
                                                nullptr, nullptr, xbuf, xhf, NN, 1);
    }

    for (int L = 0; L < 4; ++L) {
        dim3 g(157, 4);
        gemm_mfma_kernel<<<g, 256, 0, stream>>>(xhf, WctAll + L * 65536, bf[L],
                                                bsp[L], Hd, Hf, nullptr, nullptr,
                                                NN, 0);
        const int* sArr = (L < 2) ? eidB : srcR;
        const int* oArr = (L < 2) ? offB : offR;
        float* xout = (L == 3) ? (float*)d_out : xbuf;
        node_agg_kernel<<<NN / 4, 256, 0, stream>>>(Hd, Hf, sArr, oArr, xbuf,
                                                    xout, xhf, (L == 3) ? 0 : 1);
    }
    (void)n_in; (void)out_size; (void)ws_size;
}

// Round 13
// 224.152 us; speedup vs baseline: 1.2038x; 1.0762x over previous
//
#include <hip/hip_runtime.h>
#include <hip/hip_bf16.h>

#define NN 20000
#define CC 128

typedef __attribute__((ext_vector_type(8))) _Float16 half8;
typedef __attribute__((ext_vector_type(2))) _Float16 half2v;
typedef __attribute__((ext_vector_type(4))) float f32x4;

typedef const __attribute__((address_space(1))) void gv_t;
typedef __attribute__((address_space(3))) void sv_t;

// ---------- one-shot conversions: proj weights, We2, We1^T, x_prot->f16 ----------
__global__ __launch_bounds__(256) void conv_all_kernel(
    const float* __restrict__ Wf0, const float* __restrict__ Ws0,
    const float* __restrict__ Wf1, const float* __restrict__ Ws1,
    const float* __restrict__ Wf2, const float* __restrict__ Ws2,
    const float* __restrict__ Wf3, const float* __restrict__ Ws3,
    const float* __restrict__ We2, const float* __restrict__ We1,
    const float* __restrict__ xprot,
    _Float16* __restrict__ WctAll, _Float16* __restrict__ Wcte,
    _Float16* __restrict__ Wt1, _Float16* __restrict__ xp16) {
    int id = blockIdx.x * 256 + threadIdx.x;
    if (id < 262144) {
        int Lw = id >> 16;
        int i = id & 65535;
        int c = i & 511;
        int k = i >> 9;
        const float* Wfp = (Lw == 0) ? Wf0 : (Lw == 1) ? Wf1 : (Lw == 2) ? Wf2 : Wf3;
        const float* Wsp = (Lw == 0) ? Ws0 : (Lw == 1) ? Ws1 : (Lw == 2) ? Ws2 : Ws3;
        float v;
        if (c < 128) v = Wfp[k * 128 + c];
        else if (c < 256) v = Wfp[(128 + k) * 128 + (c - 128)];
        else if (c < 384) v = Wsp[k * 128 + (c - 256)];
        else v = Wsp[(128 + k) * 128 + (c - 384)];
        WctAll[Lw * 65536 + c * 128 + k] = (_Float16)v;
    } else if (id < 278528) {
        int i = id - 262144;
        int c = i & 127;
        int k = i >> 7;
        Wcte[c * 128 + k] = (_Float16)We2[k * 128 + c];
    } else if (id < 282624) {
        int i = id - 278528;
        int c = i & 127;
        int k = i >> 7;  // k < 32
        Wt1[c * 32 + k] = (_Float16)We1[k * 128 + c];
    } else {
        int i = id - 282624;  // < 640000
        xp16[i] = (_Float16)xprot[i];
    }
}

// ---------- encoder layer 1 via MFMA: (N x 32) @ (32 x 128) + b, relu -> f16 ----------
__global__ __launch_bounds__(256) void enc1_mfma_kernel(
    const _Float16* __restrict__ A, const _Float16* __restrict__ Wt1,
    const float* __restrict__ b, _Float16* __restrict__ Y) {
    int t = threadIdx.x;
    int wid = t >> 6, l = t & 63;
    int lr = l & 15, hi = l >> 4;
    int m0 = blockIdx.x * 128 + wid * 32;
    half8 af[2];
#pragma unroll
    for (int m = 0; m < 2; ++m) {
        int row = m0 + m * 16 + lr;
        half8 v = {0, 0, 0, 0, 0, 0, 0, 0};
        if (row < NN) v = *(const half8*)(A + (long)row * 32 + hi * 8);
        af[m] = v;
    }
    f32x4 acc[2][8] = {};
#pragma unroll
    for (int n = 0; n < 8; ++n) {
        int col = n * 16 + lr;
        half8 bg = *(const half8*)(Wt1 + (long)col * 32 + hi * 8);
#pragma unroll
        for (int m = 0; m < 2; ++m)
            acc[m][n] = __builtin_amdgcn_mfma_f32_16x16x32_f16(af[m], bg, acc[m][n], 0, 0, 0);
    }
#pragma unroll
    for (int n = 0; n < 8; ++n) {
        int col = n * 16 + lr;
        float bb = b[col];
#pragma unroll
        for (int m = 0; m < 2; ++m) {
#pragma unroll
            for (int q = 0; q < 4; ++q) {
                int row = m0 + m * 16 + hi * 4 + q;
                if (row < NN)
                    Y[(long)row * 128 + col] = (_Float16)fmaxf(acc[m][n][q] + bb, 0.0f);
            }
        }
    }
}

// ---------- MFMA GEMM with global_load_lds staging (r4-proven) ----------
// A f16 row-major; Wt f16 TRANSPOSED [ncol][128].
// mode 0 (proj): outH f16 [M][512] scaled by log2(e); bias0 on [0,128), bias1 on [256,384)
// mode 1 (enc2): ncol=128; outF f32 + outF16 f16 (unscaled); bias0 on all cols
__global__ __launch_bounds__(256) void gemm_mfma_kernel(
    const _Float16* __restrict__ A, const _Float16* __restrict__ Wt,
    const float* __restrict__ bias0, const float* __restrict__ bias1,
    _Float16* __restrict__ outH, float* __restrict__ outF,
    _Float16* __restrict__ outF16, int M, int mode) {
    __shared__ _Float16 lds[32768];  // 64 KB
    int t = threadIdx.x;
    int w = t >> 6, l = t & 63;
    int m0 = blockIdx.x * 128;
    int n0 = blockIdx.y * 128;
    {
        int rin = l >> 4;
        int cs = l & 15;
#pragma unroll
        for (int j = 0; j < 8; ++j) {
            int r = w * 32 + j * 4 + rin;
            int g = cs ^ (r & 7);
            int grow = m0 + r;
            if (grow > M - 1) grow = M - 1;
            const _Float16* srcA = A + (long)grow * 128 + g * 8;
            __builtin_amdgcn_global_load_lds((gv_t*)srcA,
                (sv_t*)&lds[(w * 32 + j * 4) * 128], 16, 0, 0);
            const _Float16* srcB = Wt + (long)(n0 + r) * 128 + g * 8;
            __builtin_amdgcn_global_load_lds((gv_t*)srcB,
                (sv_t*)&lds[16384 + (w * 32 + j * 4) * 128], 16, 0, 0);
        }
    }
    __syncthreads();
    int wm = w >> 1, wn = w & 1;
    int lr = l & 15, hi = l >> 4;
    f32x4 acc[4][4] = {};
#pragma unroll
    for (int ks = 0; ks < 4; ++ks) {
        int cidx = 4 * ks + hi;
        half8 af[4], bg[4];
#pragma unroll
        for (int m = 0; m < 4; ++m) {
            int row = wm * 64 + m * 16 + lr;
            af[m] = *(const half8*)(&lds[row * 128 + (cidx ^ (row & 7)) * 8]);
        }
#pragma unroll
        for (int n = 0; n < 4; ++n) {
            int row = wn * 64 + n * 16 + lr;
            bg[n] = *(const half8*)(&lds[16384 + row * 128 + (cidx ^ (row & 7)) * 8]);
        }
#pragma unroll
        for (int m = 0; m < 4; ++m)
#pragma unroll
            for (int n = 0; n < 4; ++n)
                acc[m][n] = __builtin_amdgcn_mfma_f32_16x16x32_f16(
                    af[m], bg[n], acc[m][n], 0, 0, 0);
    }
    if (mode == 0) {
        __syncthreads();
        const float S = 1.44269504f;
#pragma unroll
        for (int n = 0; n < 4; ++n) {
            int cl = wn * 64 + n * 16 + lr;
            int gcol = n0 + cl;
            float badd = (gcol < 128) ? bias0[gcol]
                       : ((gcol >= 256 && gcol < 384) ? bias1[gcol - 256] : 0.0f);
#pragma unroll
            for (int m = 0; m < 4; ++m)
#pragma unroll
                for (int q = 0; q < 4; ++q) {
                    int rl = wm * 64 + m * 16 + hi * 4 + q;
                    lds[rl * 144 + cl] = (_Float16)((acc[m][n][q] + badd) * S);
                }
        }
        __syncthreads();
#pragma unroll
        for (int i = 0; i < 8; ++i) {
            int id = t + 256 * i;
            int row = id >> 4, ch = id & 15;
            int grow = m0 + row;
            if (grow < M) {
                half8 v = *(const half8*)(&lds[row * 144 + ch * 8]);
                *(half8*)(&outH[(long)grow * 512 + n0 + ch * 8]) = v;
            }
        }
    } else {
#pragma unroll
        for (int n = 0; n < 4; ++n) {
            int gcol = n0 + wn * 64 + n * 16 + lr;
            float badd = bias0[gcol];
#pragma unroll
            for (int m = 0; m < 4; ++m)
#pragma unroll
                for (int q = 0; q < 4; ++q) {
                    int grow = m0 + wm * 64 + m * 16 + hi * 4 + q;
                    if (grow < M) {
                        float v = acc[m][n][q] + badd;
                        outF[(long)grow * 128 + gcol] = v;
                        outF16[(long)grow * 128 + gcol] = (_Float16)v;
                    }
                }
        }
    }
}

// ---------- bond CSR build ----------
__global__ __launch_bounds__(256) void count_int_kernel(
    const int* __restrict__ dst, int E, int* __restrict__ cnt) {
    int e = blockIdx.x * 256 + threadIdx.x;
    if (e < E) atomicAdd(&cnt[dst[e]], 1);
}

__global__ __launch_bounds__(1024) void scan_kernel(
    const int* __restrict__ cnt, int* __restrict__ off) {
    __shared__ int part[1024];
    int t = threadIdx.x;
    int base = t * 20;
    int loc[20];
    int s = 0;
#pragma unroll
    for (int i = 0; i < 20; ++i) {
        int idx = base + i;
        int v = (idx < NN) ? cnt[idx] : 0;
        loc[i] = s;
        s += v;
    }
    part[t] = s;
    __syncthreads();
    for (int d = 1; d < 1024; d <<= 1) {
        int v = (t >= d) ? part[t - d] : 0;
        __syncthreads();
        part[t] += v;
        __syncthreads();
    }
    int pre = (t > 0) ? part[t - 1] : 0;
#pragma unroll
    for (int i = 0; i < 20; ++i) {
        int idx = base + i;
        if (idx < NN) off[idx] = pre + loc[i];
    }
    if (t == 1023) off[NN] = part[1023];
}

__global__ __launch_bounds__(256) void scatter_kernel(
    const int* __restrict__ src, const int* __restrict__ dst, int E,
    const int* __restrict__ off, int* __restrict__ cur, int* __restrict__ eid) {
    int e = blockIdx.x * 256 + threadIdx.x;
    if (e < E) {
        int d = dst[e];
        int p = off[d] + atomicAdd(&cur[d], 1);
        eid[p] = src[e];
    }
}

// ---------- radius CSR offsets via binary search (dst sorted) ----------
__global__ __launch_bounds__(256) void csr_off_kernel(
    const int* __restrict__ dst, int E, int N1, int* __restrict__ off) {
    int n = blockIdx.x * 256 + threadIdx.x;
    if (n >= N1) return;
    int lo = 0, hi = E;
    while (lo < hi) {
        int mid = (lo + hi) >> 1;
        if (dst[mid] < n) lo = mid + 1;
        else hi = mid;
    }
    off[n] = lo;
}

// ---------- node-centric aggregation: unroll-8, upfront gathers, direct softplus ----------
// H pre-scaled by log2(e). sig = rcp(1+exp2(-f')); softplus = ln2*log2(1+exp2(s'))
// (exp2 underflow -> 0 -> log2(1)=0 exact; s' << 127 so no overflow). ln2 folded into inv.
__global__ __launch_bounds__(256) void node_agg_kernel(
    const _Float16* __restrict__ H, const int* __restrict__ srcArr,
    const int* __restrict__ off, const float* __restrict__ xin,
    float* __restrict__ xout, _Float16* __restrict__ xh, int write_h) {
    int n = blockIdx.x * 4 + (threadIdx.x >> 6);
    int nu = __builtin_amdgcn_readfirstlane(n);
    int l = threadIdx.x & 63;
    const half2v* H2 = (const half2v*)H;
    const half2v* hrow = H2 + (long)nu * 256;
    half2v fdh = hrow[l];
    half2v sdh = hrow[128 + l];
    int e0 = __builtin_amdgcn_readfirstlane(off[nu]);
    int e1 = __builtin_amdgcn_readfirstlane(off[nu + 1]);
    float ax = 0.0f, ay = 0.0f;
#define EDGEC(fv, sv)                                                         \
    {                                                                         \
        half2v fsum = fdh + (fv);                                             \
        half2v ssum = sdh + (sv);                                             \
        float fx = (float)fsum.x, fy = (float)fsum.y;                         \
        float sx = (float)ssum.x, sy = (float)ssum.y;                         \
        float rx = __builtin_amdgcn_rcpf(1.0f + __builtin_amdgcn_exp2f(-fx)); \
        float ry = __builtin_amdgcn_rcpf(1.0f + __builtin_amdgcn_exp2f(-fy)); \
        float spx = __builtin_amdgcn_logf(1.0f + __builtin_amdgcn_exp2f(sx)); \
        float spy = __builtin_amdgcn_logf(1.0f + __builtin_amdgcn_exp2f(sy)); \
        ax += rx * spx;                                                       \
        ay += ry * spy;                                                       \
    }
    int e = e0;
    for (; e + 7 < e1; e += 8) {
        half2v f[8], g[8];
#pragma unroll
        for (int j = 0; j < 8; ++j) {
            int s = srcArr[e + j];
            const half2v* h = H2 + (long)s * 256;
            f[j] = h[64 + l];
            g[j] = h[192 + l];
        }
#pragma unroll
        for (int j = 0; j < 8; ++j) EDGEC(f[j], g[j])
    }
    for (; e + 1 < e1; e += 2) {
        int s0 = srcArr[e], s1 = srcArr[e + 1];
        const half2v* h0 = H2 + (long)s0 * 256;
        const half2v* h1 = H2 + (long)s1 * 256;
        half2v f0 = h0[64 + l], g0 = h0[192 + l];
        half2v f1 = h1[64 + l], g1 = h1[192 + l];
        EDGEC(f0, g0) EDGEC(f1, g1)
    }
    if (e < e1) {
        int s0 = srcArr[e];
        const half2v* h0 = H2 + (long)s0 * 256;
        half2v f0 = h0[64 + l], g0 = h0[192 + l];
        EDGEC(f0, g0)
    }
#undef EDGEC
    // inv = ln2 / cnt  (folds softplus' ln2 back in)
    float inv = 0.6931471805599453f *
                __builtin_amdgcn_rcpf(fmaxf((float)(e1 - e0), 1.0f));
    float2 xv = ((const float2*)xin)[(long)nu * 64 + l];
    float ox = fmaxf(xv.x + ax * inv, 0.0f);
    float oy = fmaxf(xv.y + ay * inv, 0.0f);
    ((float2*)xout)[(long)nu * 64 + l] = make_float2(ox, oy);
    if (write_h) {
        half2v oh;
        oh.x = (_Float16)ox;
        oh.y = (_Float16)oy;
        ((half2v*)xh)[(long)nu * 64 + l] = oh;
    }
}

extern "C" void kernel_launch(void* const* d_in, const int* in_sizes, int n_in,
                              void* d_out, int out_size, void* d_ws, size_t ws_size,
                              hipStream_t stream) {
    const float* x_prot = (const float*)d_in[0];
    const int* eb = (const int*)d_in[2];
    const int* er = (const int*)d_in[3];
    int Eb = in_sizes[2] / 2;
    int Er = in_sizes[3] / 2;
    const float* We1 = (const float*)d_in[4];
    const float* be1 = (const float*)d_in[5];
    const float* We2 = (const float*)d_in[6];
    const float* be2 = (const float*)d_in[7];
    const float* Wf[4]  = {(const float*)d_in[8],  (const float*)d_in[12],
                           (const float*)d_in[16], (const float*)d_in[20]};
    const float* bf[4]  = {(const float*)d_in[9],  (const float*)d_in[13],
                           (const float*)d_in[17], (const float*)d_in[21]};
    const float* Wsp[4] = {(const float*)d_in[10], (const float*)d_in[14],
                           (const float*)d_in[18], (const float*)d_in[22]};
    const float* bsp[4] = {(const float*)d_in[11], (const float*)d_in[15],
                           (const float*)d_in[19], (const float*)d_in[23]};

    char* ws = (char*)d_ws;
    float*     xbuf  = (float*)ws;                        // 10,240,000
    _Float16*  xhf   = (_Float16*)(ws + 10240000);        //  5,120,000
    _Float16*  H     = (_Float16*)(ws + 15360000);        // 20,480,000
    _Float16*  xp16  = (_Float16*)(ws + 35840000);        //  1,280,000
    int*       cntI  = (int*)(ws + 37120000);             //     80,000
    int*       curB  = (int*)(ws + 37200000);             //     80,000
    int*       offB  = (int*)(ws + 37280000);             //     80,016
    int*       offR  = (int*)(ws + 37360016);             //     80,016
    int*       eidB  = (int*)(ws + 37440032);             //    320,000
    _Float16*  WctAll= (_Float16*)(ws + 37760032);        //    524,288
    _Float16*  Wcte  = (_Float16*)(ws + 38284320);        //     32,768
    _Float16*  Wt1   = (_Float16*)(ws + 38317088);        //      8,192

    const int* srcB = eb;
    const int* dstB = eb + Eb;
    const int* srcR = er;

    conv_all_kernel<<<3604, 256, 0, stream>>>(
        Wf[0], Wsp[0], Wf[1], Wsp[1], Wf[2], Wsp[2], Wf[3], Wsp[3],
        We2, We1, x_prot, WctAll, Wcte, Wt1, xp16);

    hipMemsetAsync(cntI, 0, 160000, stream);
    count_int_kernel<<<(Eb + 255) / 256, 256, 0, stream>>>(dstB, Eb, cntI);
    scan_kernel<<<1, 1024, 0, stream>>>(cntI, offB);
    scatter_kernel<<<(Eb + 255) / 256, 256, 0, stream>>>(srcB, dstB, Eb, offB, curB, eidB);
    csr_off_kernel<<<(NN + 256) / 256, 256, 0, stream>>>(er + Er, Er, NN + 1, offR);

    enc1_mfma_kernel<<<157, 256, 0, stream>>>(xp16, Wt1, be1, H);
    {
        dim3 g(157, 1);
        gemm_mfma_kernel<<<g, 256, 0, stream>>>(H, Wcte, be2, be2, nullptr,
                                                xbuf, xhf, NN, 1);
    }

    for (int L = 0; L < 4; ++L) {
        dim3 g(157, 4);
        gemm_mfma_kernel<<<g, 256, 0, stream>>>(xhf, WctAll + L * 65536, bf[L],
                                                bsp[L], H, nullptr, nullptr, NN, 0);
        const int* sArr = (L < 2) ? eidB : srcR;
        const int* oArr = (L < 2) ? offB : offR;
        float* xout = (L == 3) ? (float*)d_out : xbuf;
        node_agg_kernel<<<NN / 4, 256, 0, stream>>>(H, sArr, oArr, xbuf, xout,
                                                    xhf, (L == 3) ? 0 : 1);
    }
    (void)n_in; (void)out_size; (void)ws_size;
}